// Round 1
// baseline (196.957 us; speedup 1.0000x reference)
//
#include <hip/hip_runtime.h>

#define CH   256
#define HH   128
#define WW   128
#define HWPIX (HH * WW)      // 16384 = 2^14

// Kernel 1: addend[b*HW + pix] = mask(b,h,w) ? mean_c(x[b,:,h,w]) : 0
__global__ __launch_bounds__(256) void k_addend(
    const float* __restrict__ x,
    const float* __restrict__ bboxes,
    const int*   __restrict__ batch_idx,
    float* __restrict__ addend,
    int N)
{
    const int blocksPerImg = HWPIX / 256;              // 64
    const int b   = blockIdx.x / blocksPerImg;
    const int pix = (blockIdx.x % blocksPerImg) * 256 + threadIdx.x;
    const int h   = pix >> 7;
    const int w   = pix & (WW - 1);

    // channel-mean: stride-HW loads, coalesced across the wave
    const float* xp = x + (size_t)b * CH * HWPIX + pix;
    float s = 0.0f;
    #pragma unroll 8
    for (int c = 0; c < CH; ++c)
        s += xp[(size_t)c * HWPIX];

    // rasterize boxes for this image (batch is uniform per block)
    int inside = 0;
    for (int n = 0; n < N; ++n) {
        if (batch_idx[n] != b) continue;
        const float xc = bboxes[4 * n + 0];
        const float yc = bboxes[4 * n + 1];
        const float bw = bboxes[4 * n + 2];
        const float bh = bboxes[4 * n + 3];
        // match jnp.trunc(...).astype(int32) then max/min clamps exactly
        const int x1 = max(0,      (int)truncf((xc - bw * 0.5f) * (float)WW));
        const int y1 = max(0,      (int)truncf((yc - bh * 0.5f) * (float)HH));
        const int x2 = min(WW - 1, (int)truncf((xc + bw * 0.5f) * (float)WW));
        const int y2 = min(HH - 1, (int)truncf((yc + bh * 0.5f) * (float)HH));
        if (x2 > x1 && y2 > y1 &&
            h >= y1 && h <= y2 && w >= x1 && w <= x2)
            inside = 1;
    }

    addend[b * HWPIX + pix] = inside ? s * (1.0f / CH) : 0.0f;
}

// Kernel 2: out = x + addend[b, pix], vectorized float4, grid-stride
__global__ __launch_bounds__(256) void k_apply(
    const float4* __restrict__ x4,
    const float4* __restrict__ add4,   // addend viewed as float4 [B * HW/4]
    float4* __restrict__ out4,
    int total4)
{
    const int stride = gridDim.x * blockDim.x;
    for (int g = blockIdx.x * blockDim.x + threadIdx.x; g < total4; g += stride) {
        // element index e = 4*g ; b = e >> 22 ; pix = e & (HW-1)
        const int b    = g >> 20;                  // e >> 22
        const int pix4 = g & (HWPIX / 4 - 1);      // (e & 16383) / 4
        const float4 xv = x4[g];
        const float4 av = add4[b * (HWPIX / 4) + pix4];
        float4 o;
        o.x = xv.x + av.x;
        o.y = xv.y + av.y;
        o.z = xv.z + av.z;
        o.w = xv.w + av.w;
        out4[g] = o;
    }
}

extern "C" void kernel_launch(void* const* d_in, const int* in_sizes, int n_in,
                              void* d_out, int out_size, void* d_ws, size_t ws_size,
                              hipStream_t stream)
{
    const float* x         = (const float*)d_in[0];
    const float* bboxes    = (const float*)d_in[1];
    const int*   batch_idx = (const int*)d_in[2];
    float*       out       = (float*)d_out;
    float*       addend    = (float*)d_ws;         // needs B*H*W*4 = 1 MiB

    const int N = in_sizes[1] / 4;                 // number of boxes
    const int B = 16;

    k_addend<<<B * (HWPIX / 256), 256, 0, stream>>>(x, bboxes, batch_idx, addend, N);

    const int total4 = B * CH * HWPIX / 4;         // 16,777,216
    k_apply<<<4096, 256, 0, stream>>>((const float4*)x,
                                      (const float4*)addend,
                                      (float4*)out, total4);
}

// Round 2
// 173.980 us; speedup vs baseline: 1.1321x; 1.1321x over previous
//
#include <hip/hip_runtime.h>

#define CH     256
#define HH     128
#define WW     128
#define HWPIX  (HH * WW)        // 16384
#define TILE_PX 64              // pixels per block (half a row)
#define QUADS   16              // float4 pixel-quads per tile
#define CGROUPS 16              // channel groups
#define CPG     16              // channels per group

// One pass: read x into regs, reduce channel mean via LDS, rasterize boxes,
// write out = x + mask*mean from regs. x touches HBM exactly once each way.
__global__ __launch_bounds__(256) void k_fused(
    const float* __restrict__ x,
    const float* __restrict__ bboxes,
    const int*   __restrict__ batch_idx,
    float*       __restrict__ out,
    int N)
{
    const int tilesPerImg = HWPIX / TILE_PX;        // 256
    const int b    = blockIdx.x / tilesPerImg;
    const int tile = blockIdx.x % tilesPerImg;
    const int pix0 = tile * TILE_PX;

    const int q = threadIdx.x & (QUADS - 1);        // pixel-quad index 0..15
    const int g = threadIdx.x >> 4;                 // channel group   0..15

    const int pixq = pix0 + 4 * q;                  // first pixel of quad
    const size_t base = (size_t)b * CH * HWPIX + (size_t)(g * CPG) * HWPIX + pixq;

    const float4* __restrict__ xq = (const float4*)(x + base);

    // ---- load 16 channels x 4 pixels into registers, partial-sum ----
    float4 v[CPG];
    float4 ps = make_float4(0.f, 0.f, 0.f, 0.f);
    #pragma unroll
    for (int j = 0; j < CPG; ++j) {
        v[j] = xq[(size_t)j * (HWPIX / 4)];
        ps.x += v[j].x; ps.y += v[j].y; ps.z += v[j].z; ps.w += v[j].w;
    }

    // ---- cross-group reduce via LDS ----
    __shared__ float4 part[CGROUPS][QUADS];
    part[g][q] = ps;
    __syncthreads();

    float4 tot = make_float4(0.f, 0.f, 0.f, 0.f);
    #pragma unroll
    for (int gg = 0; gg < CGROUPS; ++gg) {
        const float4 p = part[gg][q];
        tot.x += p.x; tot.y += p.y; tot.z += p.z; tot.w += p.w;
    }

    // ---- rasterize boxes for this image (batch check is wave-uniform) ----
    const int h  = pixq >> 7;                       // row, same for all 4 px
    const int w0 = pixq & (WW - 1);
    int in0 = 0, in1 = 0, in2 = 0, in3 = 0;
    for (int n = 0; n < N; ++n) {
        if (batch_idx[n] != b) continue;
        const float xc = bboxes[4 * n + 0];
        const float yc = bboxes[4 * n + 1];
        const float bw = bboxes[4 * n + 2];
        const float bh = bboxes[4 * n + 3];
        // match jnp.trunc(...).astype(int32) then max/min clamps exactly
        const int x1 = max(0,      (int)truncf((xc - bw * 0.5f) * (float)WW));
        const int y1 = max(0,      (int)truncf((yc - bh * 0.5f) * (float)HH));
        const int x2 = min(WW - 1, (int)truncf((xc + bw * 0.5f) * (float)WW));
        const int y2 = min(HH - 1, (int)truncf((yc + bh * 0.5f) * (float)HH));
        if (!(x2 > x1 && y2 > y1)) continue;
        if (h < y1 || h > y2) continue;
        in0 |= (w0 + 0 >= x1) & (w0 + 0 <= x2);
        in1 |= (w0 + 1 >= x1) & (w0 + 1 <= x2);
        in2 |= (w0 + 2 >= x1) & (w0 + 2 <= x2);
        in3 |= (w0 + 3 >= x1) & (w0 + 3 <= x2);
    }

    const float inv = 1.0f / (float)CH;
    float4 a;
    a.x = in0 ? tot.x * inv : 0.0f;
    a.y = in1 ? tot.y * inv : 0.0f;
    a.z = in2 ? tot.z * inv : 0.0f;
    a.w = in3 ? tot.w * inv : 0.0f;

    // ---- write out = x + addend from registers ----
    float4* __restrict__ oq = (float4*)(out + base);
    #pragma unroll
    for (int j = 0; j < CPG; ++j) {
        float4 o = v[j];
        o.x += a.x; o.y += a.y; o.z += a.z; o.w += a.w;
        oq[(size_t)j * (HWPIX / 4)] = o;
    }
}

extern "C" void kernel_launch(void* const* d_in, const int* in_sizes, int n_in,
                              void* d_out, int out_size, void* d_ws, size_t ws_size,
                              hipStream_t stream)
{
    const float* x         = (const float*)d_in[0];
    const float* bboxes    = (const float*)d_in[1];
    const int*   batch_idx = (const int*)d_in[2];
    float*       out       = (float*)d_out;

    const int N = in_sizes[1] / 4;                  // 320 boxes
    const int B = 16;

    const int blocks = B * (HWPIX / TILE_PX);       // 4096
    k_fused<<<blocks, 256, 0, stream>>>(x, bboxes, batch_idx, out, N);
}